// Round 4
// baseline (547.461 us; speedup 1.0000x reference)
//
#include <hip/hip_runtime.h>
#include <hip/hip_bf16.h>

// GCN attention forward, MI355X. I/O dtype resolved at runtime (fp32 vs bf16).
// Intermediates bf16. adj ~1% sparse (~41 nz/row) -> sparse lists + masked
// softmax (scores = dots of unit vectors, |s|<=1 -> no max subtraction).
// GEMMs: mfma_f32_16x16x32_bf16, A-tiles staged in LDS k-major (padded chunk
// layout (q*(R+1)+row)*16B -> <=2-way bank aliasing on ds_read_b128 = free).
// Q/K GEMM + row-normalize + div_loss fused in one kernel (in-register
// 16-lane butterfly row sums; qn relayed via LDS for the (qn-kn)^2 partial).

#define NN    4096
#define ROWS  8192
#define OFT   256
#define CAP   128
#define NPART 256            // ROWS/32 div_loss partials
#define EPSN  1e-12f

typedef unsigned short ushort_t;
typedef __attribute__((ext_vector_type(8))) short bf16x8;
typedef __attribute__((ext_vector_type(4))) float f32x4;

__device__ __forceinline__ float lo_f(unsigned u) { union { unsigned i; float f; } c; c.i = u << 16;          return c.f; }
__device__ __forceinline__ float hi_f(unsigned u) { union { unsigned i; float f; } c; c.i = u & 0xFFFF0000u;  return c.f; }
__device__ __forceinline__ float bf2f(ushort_t u) { union { unsigned i; float f; } c; c.i = (unsigned)u << 16; return c.f; }
__device__ __forceinline__ ushort_t f2bf(float f) {
    union { float f; unsigned i; } c; c.f = f;
    unsigned r = c.i + 0x7FFFu + ((c.i >> 16) & 1u);
    return (ushort_t)(r >> 16);
}

__device__ __forceinline__ float block_sum256(float v, float* s4) {
    int lane = threadIdx.x & 63, w = threadIdx.x >> 6;
#pragma unroll
    for (int off = 32; off; off >>= 1) v += __shfl_down(v, off, 64);
    __syncthreads();
    if (lane == 0) s4[w] = v;
    __syncthreads();
    return s4[0] + s4[1] + s4[2] + s4[3];
}

// 8 consecutive k-elements of row `row` as bf16x8 (fp32 source converted).
__device__ __forceinline__ bf16x8 load_frag(const void* base, size_t row, int K,
                                            int k8, int is32)
{
    if (is32) {
        const float* p = (const float*)base + row * (size_t)K + k8;
        float4 x0 = *(const float4*)p, x1 = *(const float4*)(p + 4);
        union { bf16x8 v; ushort_t u[8]; } c;
        c.u[0] = f2bf(x0.x); c.u[1] = f2bf(x0.y); c.u[2] = f2bf(x0.z); c.u[3] = f2bf(x0.w);
        c.u[4] = f2bf(x1.x); c.u[5] = f2bf(x1.y); c.u[6] = f2bf(x1.z); c.u[7] = f2bf(x1.w);
        return c.v;
    }
    const ushort_t* p = (const ushort_t*)base + row * (size_t)K + k8;
    return *(const bf16x8*)p;
}

// Stage A[m0..m0+R) x [kc..kc+256) into LDS, k-major padded chunk layout.
template<int R>
__device__ __forceinline__ void stage_A(const void* Av, int m0, int K, int kc,
                                        int a32, ushort_t* lds)
{
#pragma unroll
    for (int u = 0; u < R / 8; ++u) {
        int c = threadIdx.x + u * 256;
        int row = c >> 5, q = c & 31;
        bf16x8 v = load_frag(Av, (size_t)(m0 + row), K, kc + q * 8, a32);
        *(bf16x8*)(lds + (size_t)(q * (R + 1) + row) * 8) = v;
    }
}

// ------------------------------------------------------------ dtype detector
__global__ void detect_dtype(const unsigned* __restrict__ w, int* __restrict__ flag)
{
    __shared__ int cs;
    int t = threadIdx.x;
    if (t == 0) cs = 0;
    __syncthreads();
    union { unsigned i; float f; } c; c.i = w[t];
    float a = fabsf(c.f);
    atomicAdd(&cs, (a > 1e-4f && a < 0.5f) ? 1 : 0);
    __syncthreads();
    if (t == 0) flag[0] = (cs >= 128) ? 1 : 0;
}

// ---------------------------------------------------------------- extract adj
__global__ __launch_bounds__(256) void extract_adj(
    const void* __restrict__ adjv, const int* __restrict__ flag,
    ushort_t* __restrict__ cols, ushort_t* __restrict__ vals, int* __restrict__ cnt)
{
    __shared__ int c;
    int r = blockIdx.x, tid = threadIdx.x;
    if (tid == 0) c = 0;
    __syncthreads();
    if (flag[0]) {
        const float4* row = (const float4*)((const float*)adjv + (size_t)r * NN);
        for (int j = tid; j < NN / 4; j += 256) {
            float4 v = row[j];
            float f[4] = {v.x, v.y, v.z, v.w};
#pragma unroll
            for (int t = 0; t < 4; ++t)
                if (f[t] > 0.f) {
                    int p = atomicAdd(&c, 1);
                    if (p < CAP) { cols[(size_t)r*CAP+p] = (ushort_t)(j*4+t); vals[(size_t)r*CAP+p] = f2bf(f[t]); }
                }
        }
    } else {
        const uint4* row4 = (const uint4*)((const ushort_t*)adjv + (size_t)r * NN);
        for (int j = tid; j < NN / 8; j += 256) {
            uint4 u = row4[j];
            unsigned uu[4] = {u.x, u.y, u.z, u.w};
#pragma unroll
            for (int t = 0; t < 4; ++t) {
                float f0 = lo_f(uu[t]), f1 = hi_f(uu[t]);
                int base = j * 8 + t * 2;
                if (f0 > 0.f) { int p = atomicAdd(&c, 1); if (p < CAP) { cols[(size_t)r*CAP+p] = (ushort_t)base;     vals[(size_t)r*CAP+p] = (ushort_t)(uu[t] & 0xFFFF); } }
                if (f1 > 0.f) { int p = atomicAdd(&c, 1); if (p < CAP) { cols[(size_t)r*CAP+p] = (ushort_t)(base+1); vals[(size_t)r*CAP+p] = (ushort_t)(uu[t] >> 16);    } }
            }
        }
    }
    __syncthreads();
    if (tid == 0) cnt[r] = (c < CAP) ? c : CAP;
}

// ------------------------------------------------------------ plain MFMA GEMM
// C[8192,256] = A[8192,K] @ W[256,K]^T. Tile: 64 rows x 128 cols per block,
// grid (2,128). A staged in LDS (full K<=512 via 256-chunks); W frags from L2.
// MODE 0: bf16 out. MODE 1: prelu -> bf16. MODE 2: prelu(x+bias) -> out dtype.
template<int MODE>
__global__ __launch_bounds__(256) void gemm_a(
    const void* __restrict__ Av, const void* __restrict__ Wv,
    void* __restrict__ Cv, int K, int a_input, const int* __restrict__ flag,
    const void* __restrict__ alpha_p, const void* __restrict__ biasv)
{
    __shared__ ushort_t Alds[32 * 65 * 8];        // R=64: 33280 B
    const int is32 = flag[0];
    const int a32 = a_input & is32;
    const int tid = threadIdx.x, wave = tid >> 6, lane = tid & 63;
    const int t16 = lane & 15, kq = lane >> 4;
    const int m0 = blockIdx.y * 64;
    const int n0 = blockIdx.x * 128;
    const int row_l = wave * 16 + t16;            // A-frag row within tile

    f32x4 acc[8];
#pragma unroll
    for (int j = 0; j < 8; ++j) acc[j] = (f32x4){0.f, 0.f, 0.f, 0.f};

    for (int kc = 0; kc < K; kc += 256) {
        __syncthreads();
        stage_A<64>(Av, m0, K, kc, a32, Alds);
        __syncthreads();
#pragma unroll
        for (int s = 0; s < 8; ++s) {
            bf16x8 a = *(const bf16x8*)(Alds + (size_t)((s * 4 + kq) * 65 + row_l) * 8);
#pragma unroll
            for (int j = 0; j < 8; ++j) {
                bf16x8 b = load_frag(Wv, (size_t)(n0 + j * 16 + t16), K, kc + s * 32 + kq * 8, is32);
                acc[j] = __builtin_amdgcn_mfma_f32_16x16x32_bf16(a, b, acc[j], 0, 0, 0);
            }
        }
    }

    float alpha = 0.f;
    if (MODE) alpha = is32 ? *(const float*)alpha_p : bf2f(*(const ushort_t*)alpha_p);
#pragma unroll
    for (int j = 0; j < 8; ++j) {
        int col = n0 + j * 16 + t16;
        float bv = 0.f;
        if (MODE == 2) bv = is32 ? ((const float*)biasv)[col] : bf2f(((const ushort_t*)biasv)[col]);
#pragma unroll
        for (int r = 0; r < 4; ++r) {
            int row = m0 + wave * 16 + kq * 4 + r;
            float x = acc[j][r];
            if (MODE == 2) x += bv;
            if (MODE) x = (x >= 0.f) ? x : alpha * x;
            size_t off = (size_t)row * OFT + col;
            if (MODE == 2 && is32) ((float*)Cv)[off] = x;
            else                   ((ushort_t*)Cv)[off] = f2bf(x);
        }
    }
}

// ------------------------- fused Q/K GEMM + row-normalize + div_loss partial
// Block: 32 rows, full 256 cols. Waves 0,1 -> q rows 0-15/16-31; waves 2,3 -> k.
// Row L2-norm via in-register 16-lane butterfly; qn relayed via LDS (fp32);
// k-waves accumulate per-row sum (qn-kn)^2 -> part[block].
__global__ __launch_bounds__(256) void gemm_qk_norm(
    const ushort_t* __restrict__ A, const void* __restrict__ Wq,
    const void* __restrict__ Wk, ushort_t* __restrict__ qo,
    ushort_t* __restrict__ ko, float* __restrict__ part,
    const int* __restrict__ flag)
{
    __shared__ ushort_t Alds[32 * 33 * 8];        // R=32: 16896 B
    __shared__ float qn_lds[32 * 256];            // 32 KB
    __shared__ float rowloss[32];
    __shared__ float s4[4];
    const int is32 = flag[0];
    const int tid = threadIdx.x, wave = tid >> 6, lane = tid & 63;
    const int t16 = lane & 15, kq = lane >> 4;
    const int m0 = blockIdx.x * 32;
    const int isK = wave >> 1;                    // 0: q-matrix, 1: k-matrix
    const int wr = wave & 1;                      // row half (16 rows)
    const int row_l = wr * 16 + t16;
    const void* Wv = isK ? Wk : Wq;
    ushort_t* Co = isK ? ko : qo;

    f32x4 acc[16];
#pragma unroll
    for (int j = 0; j < 16; ++j) acc[j] = (f32x4){0.f, 0.f, 0.f, 0.f};

    stage_A<32>(A, m0, 256, 0, 0, Alds);
    __syncthreads();
#pragma unroll
    for (int s = 0; s < 8; ++s) {
        bf16x8 a = *(const bf16x8*)(Alds + (size_t)((s * 4 + kq) * 33 + row_l) * 8);
#pragma unroll
        for (int j = 0; j < 16; ++j) {
            bf16x8 b = load_frag(Wv, (size_t)(j * 16 + t16), 256, s * 32 + kq * 8, is32);
            acc[j] = __builtin_amdgcn_mfma_f32_16x16x32_bf16(a, b, acc[j], 0, 0, 0);
        }
    }

    // Row sums of squares (rows: wr*16 + kq*4 + r), butterfly over t16.
    float inv[4];
#pragma unroll
    for (int r = 0; r < 4; ++r) {
        float s = 0.f;
#pragma unroll
        for (int j = 0; j < 16; ++j) { float v = acc[j][r]; s += v * v; }
#pragma unroll
        for (int off = 1; off < 16; off <<= 1) s += __shfl_xor(s, off, 16);
        inv[r] = 1.f / fmaxf(sqrtf(s), EPSN);
    }

    __syncthreads();   // all waves done with Alds / entering qn_lds phase
#pragma unroll
    for (int j = 0; j < 16; ++j) {
        int col = j * 16 + t16;
#pragma unroll
        for (int r = 0; r < 4; ++r) {
            float v = acc[j][r] * inv[r];
            acc[j][r] = v;
            int row_loc = wr * 16 + kq * 4 + r;
            Co[(size_t)(m0 + row_loc) * OFT + col] = f2bf(v);
            if (!isK) qn_lds[row_loc * 256 + col] = v;
        }
    }
    __syncthreads();
    if (isK) {
        float dl[4] = {0.f, 0.f, 0.f, 0.f};
#pragma unroll
        for (int j = 0; j < 16; ++j) {
            int col = j * 16 + t16;
#pragma unroll
            for (int r = 0; r < 4; ++r) {
                int row_loc = wr * 16 + kq * 4 + r;
                float d = qn_lds[row_loc * 256 + col] - acc[j][r];
                dl[r] += d * d;
            }
        }
#pragma unroll
        for (int r = 0; r < 4; ++r) {
#pragma unroll
            for (int off = 1; off < 16; off <<= 1) dl[r] += __shfl_xor(dl[r], off, 16);
            if (t16 == 0) rowloss[wr * 16 + kq * 4 + r] = dl[r];
        }
    }
    __syncthreads();
    float s = (tid < 32) ? rowloss[tid] : 0.f;
    s = block_sum256(s, s4);
    if (tid == 0) part[blockIdx.x] = s;
}

// ------------------------------------------------------------------- SpMM
__global__ __launch_bounds__(256) void spmm(
    const ushort_t* __restrict__ sf, const ushort_t* __restrict__ cols,
    const ushort_t* __restrict__ vals, const int* __restrict__ cnt,
    ushort_t* __restrict__ outb)
{
    __shared__ int   lc[CAP];
    __shared__ float lv[CAP];
    int r = blockIdx.x, tid = threadIdx.x;
    int b = r >> 12;
    int n = cnt[r];
    for (int i = tid; i < n; i += 256) { lc[i] = cols[(size_t)r*CAP + i]; lv[i] = bf2f(vals[(size_t)r*CAP + i]); }
    __syncthreads();
    const ushort_t* base = sf + ((size_t)b << 12) * OFT;
    float acc = 0.f;
    for (int i = 0; i < n; ++i) acc += lv[i] * bf2f(base[(size_t)lc[i] * OFT + tid]);
    outb[(size_t)r * OFT + tid] = f2bf(acc);
}

// ------------------------------------- fused masked attention + ctx per row
__global__ __launch_bounds__(256) void attn_ctx(
    const ushort_t* __restrict__ q, const ushort_t* __restrict__ k,
    const ushort_t* __restrict__ outb, const ushort_t* __restrict__ cols,
    const int* __restrict__ cnt, ushort_t* __restrict__ ctx)
{
    __shared__ float qs[OFT];
    __shared__ float es[CAP];
    __shared__ int   lc[CAP];
    __shared__ float s4[4];
    int r = blockIdx.x, tid = threadIdx.x;
    int b = r >> 12;
    int n = cnt[r];
    qs[tid] = bf2f(q[(size_t)r * OFT + tid]);
    for (int i = tid; i < n; i += 256) lc[i] = cols[(size_t)r * CAP + i];
    __syncthreads();
    int wave = tid >> 6, lane = tid & 63;
    const ushort_t* kbase = k + ((size_t)b << 12) * OFT;
    for (int i = wave; i < n; i += 4) {
        const ushort_t* krow = kbase + (size_t)lc[i] * OFT;
        uint2 kv = *(const uint2*)(krow + lane * 4);
        float4 qv = *(const float4*)(qs + lane * 4);
        float d = lo_f(kv.x)*qv.x + hi_f(kv.x)*qv.y + lo_f(kv.y)*qv.z + hi_f(kv.y)*qv.w;
#pragma unroll
        for (int off = 32; off; off >>= 1) d += __shfl_down(d, off, 64);
        if (lane == 0) es[i] = __expf(d);
    }
    __syncthreads();
    float s = 0.f;
    for (int i = tid; i < n; i += 256) s += es[i];
    s = block_sum256(s, s4);
    float inv = 1.f / fmaxf(s, 1e-30f);
    const ushort_t* obase = outb + ((size_t)b << 12) * OFT;
    float acc = 0.f;
    for (int i = 0; i < n; ++i) acc += es[i] * bf2f(obase[(size_t)lc[i] * OFT + tid]);
    ctx[(size_t)r * OFT + tid] = f2bf(acc * inv);
}

__global__ __launch_bounds__(256) void finalize_loss(
    const float* __restrict__ part, void* __restrict__ out, const int* __restrict__ flag)
{
    __shared__ float s4[4];
    int tid = threadIdx.x;
    float s = 0.f;
    for (int i = tid; i < NPART; i += 256) s += part[i];
    s = block_sum256(s, s4);
    if (tid == 0) {
        float v = s * (1.f / 8192.f);
        if (flag[0]) ((float*)out)[(size_t)ROWS * OFT] = v;
        else         ((ushort_t*)out)[(size_t)ROWS * OFT] = f2bf(v);
    }
}

// ------------------------------------------------------------------- launch
extern "C" void kernel_launch(void* const* d_in, const int* in_sizes, int n_in,
                              void* d_out, int out_size, void* d_ws, size_t ws_size,
                              hipStream_t stream)
{
    const void* seq   = d_in[0];
    const void* adj   = d_in[1];
    const void* W_fc  = d_in[2];
    const void* W_q   = d_in[3];
    const void* W_k   = d_in[4];
    const void* W_v1  = d_in[5];
    const void* W_v2  = d_in[6];
    const void* a_v   = d_in[7];
    const void* a_act = d_in[8];
    const void* bias  = d_in[9];

    char* w = (char*)d_ws;
    ushort_t* regA = (ushort_t*)w;                     // seq_fts -> q -> ctx
    ushort_t* regK = (ushort_t*)(w + (4u << 20));      // k
    ushort_t* regC = (ushort_t*)(w + (8u << 20));      // outb -> h
    ushort_t* cols = (ushort_t*)(w + (12u << 20));
    ushort_t* vals = (ushort_t*)(w + (14u << 20));
    int*      cnt  = (int*)(w + (16u << 20));
    int*      flag = (int*)(w + (16u << 20) + ROWS * sizeof(int));
    float*    part = (float*)(w + (16u << 20) + ROWS * sizeof(int) + 256);

    dim3 ga(2, 128), blk(256);

    detect_dtype<<<1, 256, 0, stream>>>((const unsigned*)W_fc, flag);
    extract_adj<<<ROWS, 256, 0, stream>>>(adj, flag, cols, vals, cnt);
    gemm_a<0><<<ga, blk, 0, stream>>>(seq, W_fc, regA, 512, 1, flag, nullptr, nullptr);
    spmm<<<ROWS, 256, 0, stream>>>(regA, cols, vals, cnt, regC);
    gemm_qk_norm<<<NPART, blk, 0, stream>>>(regC, W_q, W_k, regA, regK, part, flag);
    attn_ctx<<<ROWS, 256, 0, stream>>>(regA, regK, regC, cols, cnt, regA);
    gemm_a<1><<<ga, blk, 0, stream>>>(regA, W_v1, regC, 256, 0, flag, a_v, nullptr);
    gemm_a<2><<<ga, blk, 0, stream>>>(regC, W_v2, d_out, 256, 0, flag, a_act, bias);
    finalize_loss<<<1, 256, 0, stream>>>(part, d_out, flag);
}

// Round 5
// 375.737 us; speedup vs baseline: 1.4570x; 1.4570x over previous
//
#include <hip/hip_runtime.h>
#include <hip/hip_bf16.h>

// GCN attention forward, MI355X. I/O dtype resolved at runtime (fp32 vs bf16).
// Intermediates bf16. adj ~1% sparse (~41 nz/row) -> sparse lists + masked
// softmax (scores = dots of unit vectors, |s|<=1 -> no max subtraction).
// GEMM: mfma_f32_16x16x32_bf16; A AND W chunks double-buffered in LDS
// (k-major padded chunk layout -> uniform 8/bank on b128 = conflict-free),
// 64x64 tile, 512 blocks (2/CU), waves on 32x32 subtiles, reg prefetch,
// one barrier per chunk. R4 lesson: per-lane global W-frag loads before each
// MFMA = 88us/GEMM of exposed latency + 16MB HBM W re-fetch. W goes via LDS.

#define NN    4096
#define ROWS  8192
#define OFT   256
#define CAP   128
#define EPSN  1e-12f

typedef unsigned short ushort_t;
typedef __attribute__((ext_vector_type(8))) short bf16x8;
typedef __attribute__((ext_vector_type(4))) float f32x4;

__device__ __forceinline__ float lo_f(unsigned u) { union { unsigned i; float f; } c; c.i = u << 16;          return c.f; }
__device__ __forceinline__ float hi_f(unsigned u) { union { unsigned i; float f; } c; c.i = u & 0xFFFF0000u;  return c.f; }
__device__ __forceinline__ float bf2f(ushort_t u) { union { unsigned i; float f; } c; c.i = (unsigned)u << 16; return c.f; }
__device__ __forceinline__ ushort_t f2bf(float f) {
    union { float f; unsigned i; } c; c.f = f;
    unsigned r = c.i + 0x7FFFu + ((c.i >> 16) & 1u);
    return (ushort_t)(r >> 16);
}

__device__ __forceinline__ float block_sum256(float v, float* s4) {
    int lane = threadIdx.x & 63, w = threadIdx.x >> 6;
#pragma unroll
    for (int off = 32; off; off >>= 1) v += __shfl_down(v, off, 64);
    __syncthreads();
    if (lane == 0) s4[w] = v;
    __syncthreads();
    return s4[0] + s4[1] + s4[2] + s4[3];
}

__device__ __forceinline__ bf16x8 load_frag(const void* base, size_t row, int K,
                                            int k8, int is32)
{
    if (is32) {
        const float* p = (const float*)base + row * (size_t)K + k8;
        float4 x0 = *(const float4*)p, x1 = *(const float4*)(p + 4);
        union { bf16x8 v; ushort_t u[8]; } c;
        c.u[0] = f2bf(x0.x); c.u[1] = f2bf(x0.y); c.u[2] = f2bf(x0.z); c.u[3] = f2bf(x0.w);
        c.u[4] = f2bf(x1.x); c.u[5] = f2bf(x1.y); c.u[6] = f2bf(x1.z); c.u[7] = f2bf(x1.w);
        return c.v;
    }
    const ushort_t* p = (const ushort_t*)base + row * (size_t)K + k8;
    return *(const bf16x8*)p;
}

// ------------------------------------------------------------ dtype detector
__global__ void detect_dtype(const unsigned* __restrict__ w, int* __restrict__ flag)
{
    __shared__ int cs;
    int t = threadIdx.x;
    if (t == 0) cs = 0;
    __syncthreads();
    union { unsigned i; float f; } c; c.i = w[t];
    float a = fabsf(c.f);
    atomicAdd(&cs, (a > 1e-4f && a < 0.5f) ? 1 : 0);
    __syncthreads();
    if (t == 0) flag[0] = (cs >= 128) ? 1 : 0;
}

// ---------------------------------------------------------------- extract adj
__global__ __launch_bounds__(256) void extract_adj(
    const void* __restrict__ adjv, const int* __restrict__ flag,
    ushort_t* __restrict__ cols, ushort_t* __restrict__ vals, int* __restrict__ cnt)
{
    __shared__ int c;
    int r = blockIdx.x, tid = threadIdx.x;
    if (tid == 0) c = 0;
    __syncthreads();
    if (flag[0]) {
        const float4* row = (const float4*)((const float*)adjv + (size_t)r * NN);
        for (int j = tid; j < NN / 4; j += 256) {
            float4 v = row[j];
            float f[4] = {v.x, v.y, v.z, v.w};
#pragma unroll
            for (int t = 0; t < 4; ++t)
                if (f[t] > 0.f) {
                    int p = atomicAdd(&c, 1);
                    if (p < CAP) { cols[(size_t)r*CAP+p] = (ushort_t)(j*4+t); vals[(size_t)r*CAP+p] = f2bf(f[t]); }
                }
        }
    } else {
        const uint4* row4 = (const uint4*)((const ushort_t*)adjv + (size_t)r * NN);
        for (int j = tid; j < NN / 8; j += 256) {
            uint4 u = row4[j];
            unsigned uu[4] = {u.x, u.y, u.z, u.w};
#pragma unroll
            for (int t = 0; t < 4; ++t) {
                float f0 = lo_f(uu[t]), f1 = hi_f(uu[t]);
                int base = j * 8 + t * 2;
                if (f0 > 0.f) { int p = atomicAdd(&c, 1); if (p < CAP) { cols[(size_t)r*CAP+p] = (ushort_t)base;     vals[(size_t)r*CAP+p] = (ushort_t)(uu[t] & 0xFFFF); } }
                if (f1 > 0.f) { int p = atomicAdd(&c, 1); if (p < CAP) { cols[(size_t)r*CAP+p] = (ushort_t)(base+1); vals[(size_t)r*CAP+p] = (ushort_t)(uu[t] >> 16);    } }
            }
        }
    }
    __syncthreads();
    if (tid == 0) cnt[r] = (c < CAP) ? c : CAP;
}

// ------------------------------------------------------------ MFMA GEMM v2
// C[8192,256] = A[8192,K] @ W[256,K]^T. Tile 64x64, grid (4,128)=512 blocks.
// A+W chunks (KC=64) double-buffered in LDS; wave w -> 32x32 subtile
// ((w>>1)*32 rows, (w&1)*32 cols). One barrier per chunk.
// MODE 0: bf16 out. MODE 1: prelu -> bf16. MODE 2: prelu(x+bias) -> out dtype.
template<int MODE>
__global__ __launch_bounds__(256) void gemm_b(
    const void* __restrict__ Av, const void* __restrict__ Wv,
    void* __restrict__ Cv, int K, int a_input, const int* __restrict__ flag,
    const void* __restrict__ alpha_p, const void* __restrict__ biasv)
{
    __shared__ ushort_t Al[2][8 * 65 * 8];   // 8320 B per buf
    __shared__ ushort_t Wl[2][8 * 65 * 8];
    const int is32 = flag[0];
    const int a32 = a_input & is32;
    const int tid = threadIdx.x, wave = tid >> 6, lane = tid & 63;
    const int t16 = lane & 15, kq = lane >> 4;
    const int m0 = blockIdx.y * 64, n0 = blockIdx.x * 64;
    const int ldr = tid >> 3, ldq = tid & 7;          // staging map (coalesced)
    const int wr = (wave >> 1) * 32, wc = (wave & 1) * 32;
    const int NC = K >> 6;

    f32x4 acc[2][2];
#pragma unroll
    for (int i = 0; i < 2; ++i)
#pragma unroll
        for (int j = 0; j < 2; ++j) acc[i][j] = (f32x4){0.f, 0.f, 0.f, 0.f};

    // prefetch chunk 0
    bf16x8 pa0 = load_frag(Av, (size_t)(m0 + ldr),      K, ldq * 8, a32);
    bf16x8 pa1 = load_frag(Av, (size_t)(m0 + ldr + 32), K, ldq * 8, a32);
    bf16x8 pw0 = load_frag(Wv, (size_t)(n0 + ldr),      K, ldq * 8, is32);
    bf16x8 pw1 = load_frag(Wv, (size_t)(n0 + ldr + 32), K, ldq * 8, is32);

    for (int c = 0; c < NC; ++c) {
        const int buf = c & 1;
        *(bf16x8*)(Al[buf] + (size_t)(ldq * 65 + ldr) * 8)      = pa0;
        *(bf16x8*)(Al[buf] + (size_t)(ldq * 65 + ldr + 32) * 8) = pa1;
        *(bf16x8*)(Wl[buf] + (size_t)(ldq * 65 + ldr) * 8)      = pw0;
        *(bf16x8*)(Wl[buf] + (size_t)(ldq * 65 + ldr + 32) * 8) = pw1;
        __syncthreads();
        if (c + 1 < NC) {   // prefetch next chunk; loads drain during compute
            int k8 = (c + 1) * 64 + ldq * 8;
            pa0 = load_frag(Av, (size_t)(m0 + ldr),      K, k8, a32);
            pa1 = load_frag(Av, (size_t)(m0 + ldr + 32), K, k8, a32);
            pw0 = load_frag(Wv, (size_t)(n0 + ldr),      K, k8, is32);
            pw1 = load_frag(Wv, (size_t)(n0 + ldr + 32), K, k8, is32);
        }
#pragma unroll
        for (int s = 0; s < 2; ++s) {
            const int kb = (s * 4 + kq) * 65;
            bf16x8 a0 = *(const bf16x8*)(Al[buf] + (size_t)(kb + wr + t16) * 8);
            bf16x8 a1 = *(const bf16x8*)(Al[buf] + (size_t)(kb + wr + 16 + t16) * 8);
            bf16x8 b0 = *(const bf16x8*)(Wl[buf] + (size_t)(kb + wc + t16) * 8);
            bf16x8 b1 = *(const bf16x8*)(Wl[buf] + (size_t)(kb + wc + 16 + t16) * 8);
            acc[0][0] = __builtin_amdgcn_mfma_f32_16x16x32_bf16(a0, b0, acc[0][0], 0, 0, 0);
            acc[0][1] = __builtin_amdgcn_mfma_f32_16x16x32_bf16(a0, b1, acc[0][1], 0, 0, 0);
            acc[1][0] = __builtin_amdgcn_mfma_f32_16x16x32_bf16(a1, b0, acc[1][0], 0, 0, 0);
            acc[1][1] = __builtin_amdgcn_mfma_f32_16x16x32_bf16(a1, b1, acc[1][1], 0, 0, 0);
        }
        // no trailing barrier needed: next writes go to the other buffer, and
        // the c+2 reuse of this buffer is fenced by the next iteration's sync.
    }

    float alpha = 0.f;
    if (MODE) alpha = is32 ? *(const float*)alpha_p : bf2f(*(const ushort_t*)alpha_p);
#pragma unroll
    for (int i = 0; i < 2; ++i) {
#pragma unroll
        for (int j = 0; j < 2; ++j) {
            int col = n0 + wc + j * 16 + t16;
            float bv = 0.f;
            if (MODE == 2) bv = is32 ? ((const float*)biasv)[col] : bf2f(((const ushort_t*)biasv)[col]);
#pragma unroll
            for (int r = 0; r < 4; ++r) {
                int row = m0 + wr + i * 16 + kq * 4 + r;
                float x = acc[i][j][r];
                if (MODE == 2) x += bv;
                if (MODE) x = (x >= 0.f) ? x : alpha * x;
                size_t off = (size_t)row * OFT + col;
                if (MODE == 2 && is32) ((float*)Cv)[off] = x;
                else                   ((ushort_t*)Cv)[off] = f2bf(x);
            }
        }
    }
}

// ------------------------------------------------------------------- SpMM
__global__ __launch_bounds__(256) void spmm(
    const ushort_t* __restrict__ sf, const ushort_t* __restrict__ cols,
    const ushort_t* __restrict__ vals, const int* __restrict__ cnt,
    ushort_t* __restrict__ outb)
{
    __shared__ int   lc[CAP];
    __shared__ float lv[CAP];
    int r = blockIdx.x, tid = threadIdx.x;
    int b = r >> 12;
    int n = cnt[r];
    for (int i = tid; i < n; i += 256) { lc[i] = cols[(size_t)r*CAP + i]; lv[i] = bf2f(vals[(size_t)r*CAP + i]); }
    __syncthreads();
    const ushort_t* base = sf + ((size_t)b << 12) * OFT;
    float acc = 0.f;
    for (int i = 0; i < n; ++i) acc += lv[i] * bf2f(base[(size_t)lc[i] * OFT + tid]);
    outb[(size_t)r * OFT + tid] = f2bf(acc);
}

// ----------------------------------------- normalize q,k + div_loss partials
__global__ __launch_bounds__(256) void normalize_divloss(
    ushort_t* __restrict__ q, ushort_t* __restrict__ k, float* __restrict__ part)
{
    __shared__ float s4[4];
    int r = blockIdx.x, tid = threadIdx.x;
    size_t idx = (size_t)r * OFT + tid;
    float qv = bf2f(q[idx]), kv = bf2f(k[idx]);
    float sq = block_sum256(qv * qv, s4);
    float sk = block_sum256(kv * kv, s4);
    float qn = qv / fmaxf(sqrtf(sq), EPSN);
    float kn = kv / fmaxf(sqrtf(sk), EPSN);
    q[idx] = f2bf(qn); k[idx] = f2bf(kn);
    float d = qn - kn;
    float sd = block_sum256(d * d, s4);
    if (tid == 0) part[r] = sd;     // per-row partial; no same-address atomic
}

// ------------------------------------- fused masked attention + ctx per row
__global__ __launch_bounds__(256) void attn_ctx(
    const ushort_t* __restrict__ q, const ushort_t* __restrict__ k,
    const ushort_t* __restrict__ outb, const ushort_t* __restrict__ cols,
    const int* __restrict__ cnt, ushort_t* __restrict__ ctx)
{
    __shared__ float qs[OFT];
    __shared__ float es[CAP];
    __shared__ int   lc[CAP];
    __shared__ float s4[4];
    int r = blockIdx.x, tid = threadIdx.x;
    int b = r >> 12;
    int n = cnt[r];
    qs[tid] = bf2f(q[(size_t)r * OFT + tid]);
    for (int i = tid; i < n; i += 256) lc[i] = cols[(size_t)r * CAP + i];
    __syncthreads();
    int wave = tid >> 6, lane = tid & 63;
    const ushort_t* kbase = k + ((size_t)b << 12) * OFT;
    for (int i = wave; i < n; i += 4) {
        const ushort_t* krow = kbase + (size_t)lc[i] * OFT;
        uint2 kv = *(const uint2*)(krow + lane * 4);
        float4 qv = *(const float4*)(qs + lane * 4);
        float d = lo_f(kv.x)*qv.x + hi_f(kv.x)*qv.y + lo_f(kv.y)*qv.z + hi_f(kv.y)*qv.w;
#pragma unroll
        for (int off = 32; off; off >>= 1) d += __shfl_down(d, off, 64);
        if (lane == 0) es[i] = __expf(d);
    }
    __syncthreads();
    float s = 0.f;
    for (int i = tid; i < n; i += 256) s += es[i];
    s = block_sum256(s, s4);
    float inv = 1.f / fmaxf(s, 1e-30f);
    const ushort_t* obase = outb + ((size_t)b << 12) * OFT;
    float acc = 0.f;
    for (int i = 0; i < n; ++i) acc += es[i] * bf2f(obase[(size_t)lc[i] * OFT + tid]);
    ctx[(size_t)r * OFT + tid] = f2bf(acc * inv);
}

__global__ __launch_bounds__(256) void finalize_loss(
    const float* __restrict__ part, void* __restrict__ out, const int* __restrict__ flag)
{
    __shared__ float s4[4];
    int tid = threadIdx.x;
    float s = 0.f;
    for (int i = tid; i < ROWS; i += 256) s += part[i];
    s = block_sum256(s, s4);
    if (tid == 0) {
        float v = s * (1.f / 8192.f);
        if (flag[0]) ((float*)out)[(size_t)ROWS * OFT] = v;
        else         ((ushort_t*)out)[(size_t)ROWS * OFT] = f2bf(v);
    }
}

// ------------------------------------------------------------------- launch
extern "C" void kernel_launch(void* const* d_in, const int* in_sizes, int n_in,
                              void* d_out, int out_size, void* d_ws, size_t ws_size,
                              hipStream_t stream)
{
    const void* seq   = d_in[0];
    const void* adj   = d_in[1];
    const void* W_fc  = d_in[2];
    const void* W_q   = d_in[3];
    const void* W_k   = d_in[4];
    const void* W_v1  = d_in[5];
    const void* W_v2  = d_in[6];
    const void* a_v   = d_in[7];
    const void* a_act = d_in[8];
    const void* bias  = d_in[9];

    char* w = (char*)d_ws;
    ushort_t* regA = (ushort_t*)w;                     // seq_fts -> q -> ctx
    ushort_t* regK = (ushort_t*)(w + (4u << 20));      // k
    ushort_t* regC = (ushort_t*)(w + (8u << 20));      // outb -> h
    ushort_t* cols = (ushort_t*)(w + (12u << 20));
    ushort_t* vals = (ushort_t*)(w + (14u << 20));
    int*      cnt  = (int*)(w + (16u << 20));
    int*      flag = (int*)(w + (16u << 20) + ROWS * sizeof(int));
    float*    part = (float*)(w + (16u << 20) + ROWS * sizeof(int) + 256);

    dim3 gg(4, 128), blk(256);   // 512 blocks -> 2 blocks/CU

    detect_dtype<<<1, 256, 0, stream>>>((const unsigned*)W_fc, flag);
    extract_adj<<<ROWS, 256, 0, stream>>>(adj, flag, cols, vals, cnt);
    gemm_b<0><<<gg, blk, 0, stream>>>(seq, W_fc, regA, 512, 1, flag, nullptr, nullptr);
    spmm<<<ROWS, 256, 0, stream>>>(regA, cols, vals, cnt, regC);
    gemm_b<0><<<gg, blk, 0, stream>>>(regC, W_q, regA, 256, 0, flag, nullptr, nullptr);
    gemm_b<0><<<gg, blk, 0, stream>>>(regC, W_k, regK, 256, 0, flag, nullptr, nullptr);
    normalize_divloss<<<ROWS, 256, 0, stream>>>(regA, regK, part);
    attn_ctx<<<ROWS, 256, 0, stream>>>(regA, regK, regC, cols, cnt, regA);
    gemm_b<1><<<gg, blk, 0, stream>>>(regA, W_v1, regC, 256, 0, flag, a_v, nullptr);
    gemm_b<2><<<gg, blk, 0, stream>>>(regC, W_v2, d_out, 256, 0, flag, a_act, bias);
    finalize_loss<<<1, 256, 0, stream>>>(part, d_out, flag);
}